// Round 5
// baseline (502.548 us; speedup 1.0000x reference)
//
#include <hip/hip_runtime.h>
#include <hip/hip_bf16.h>
#include <cstdint>
#include <cstddef>

#define LN_EPS 1e-5f
#define B_    8
#define HW_   64
#define C_    256
#define NTOK  (B_ * HW_ * HW_)   // 32768
#define HEADS_ 8
#define DH_    32

// -------------------- per-token LN stats --------------------
// stats[tok] = {m1, r1, m2, r2}: LN2(LN1(x)) = ((x-m1)*r1*g1 + b1 - m2)*r2*g2 + b2
__global__ __launch_bounds__(256) void ln_stats_kernel(
    const float* __restrict__ x, const float* __restrict__ g1,
    const float* __restrict__ b1, float4* __restrict__ stats)
{
    const int gid  = blockIdx.x * 256 + threadIdx.x;
    const int tok  = gid >> 6;
    const int lane = gid & 63;
    if (tok >= NTOK) return;
    const float4 xv = reinterpret_cast<const float4*>(x + (size_t)tok * C_)[lane];
    float s  = xv.x + xv.y + xv.z + xv.w;
    float sq = xv.x*xv.x + xv.y*xv.y + xv.z*xv.z + xv.w*xv.w;
    for (int off = 32; off; off >>= 1) {
        s  += __shfl_xor(s, off);
        sq += __shfl_xor(sq, off);
    }
    const float m1 = s * (1.0f / 256.0f);
    const float r1 = rsqrtf(fmaxf(sq * (1.0f / 256.0f) - m1 * m1, 0.0f) + LN_EPS);
    const float4 g = reinterpret_cast<const float4*>(g1)[lane];
    const float4 b = reinterpret_cast<const float4*>(b1)[lane];
    const float y0 = (xv.x - m1) * r1 * g.x + b.x;
    const float y1 = (xv.y - m1) * r1 * g.y + b.y;
    const float y2 = (xv.z - m1) * r1 * g.z + b.z;
    const float y3 = (xv.w - m1) * r1 * g.w + b.w;
    float s2  = y0 + y1 + y2 + y3;
    float sq2 = y0*y0 + y1*y1 + y2*y2 + y3*y3;
    for (int off = 32; off; off >>= 1) {
        s2  += __shfl_xor(s2, off);
        sq2 += __shfl_xor(sq2, off);
    }
    const float m2 = s2 * (1.0f / 256.0f);
    const float r2 = rsqrtf(fmaxf(sq2 * (1.0f / 256.0f) - m2 * m2, 0.0f) + LN_EPS);
    if (lane == 0) stats[tok] = make_float4(m1, r1, m2, r2);
}

// -------------------- qkv = LN2(LN1(x)) @ w_qkv  (fp32, 8x8 microtile, prefetch) ------
// M=32768, N=768, K=256. BM=BN=128, BK=32, 256 threads, 8x8 microtile.
// LN fold:  h[t][c] = u1[c]*(alpha[t]*x - delta[t]) + (beta[t]*u2[c] - gamma[t]*u3[c] + u4[c])
//   u1=g1*g2, u2=g2*b1, u3=g2, u4=b2  (staged once per block in LDS)
//   alpha=r1*r2, beta=r2, gamma=r2*m2, delta=m1*r1*r2
__global__ __launch_bounds__(256) void qkv_kernel(
    const float* __restrict__ x, const float4* __restrict__ stats,
    const float* __restrict__ g1, const float* __restrict__ b1,
    const float* __restrict__ g2, const float* __restrict__ b2,
    const float* __restrict__ w, float* __restrict__ qkv)
{
    __shared__ float At[32][130];     // [k][token row]
    __shared__ float Bt[32][132];     // [k][n]
    __shared__ float u_lds[4][256];   // u1,u2,u3,u4
    const int tid  = threadIdx.x;
    const int tok0 = blockIdx.y * 128;
    const int n0   = blockIdx.x * 128;
    const int ty = tid >> 4, tx = tid & 15;    // microtile: rows ty*8.., cols tx*4 & 64+tx*4
    const int ar  = tid >> 1;                  // A staging row 0..127
    const int asb = (tid & 1) * 4;             // A staging float4-chunk base

    // per-channel constants -> LDS (one channel per thread)
    {
        const float g2v = g2[tid];
        u_lds[0][tid] = g1[tid] * g2v;
        u_lds[1][tid] = g2v * b1[tid];
        u_lds[2][tid] = g2v;
        u_lds[3][tid] = b2[tid];
    }

    const float4 s4 = stats[tok0 + ar];
    const float alpha = s4.y * s4.w;
    const float beta  = s4.w;
    const float gamma = s4.z * s4.w;
    const float delta = s4.x * s4.y * s4.w;
    const float* xrow = x + (size_t)(tok0 + ar) * C_;

    float acc[8][8] = {};
    float4 av[4];   // prefetched x (raw; LN fold applied at LDS-write)
    float4 bv[4];

    auto load_tiles = [&](const int it) {
        const int k0 = it * 32;
        #pragma unroll
        for (int u = 0; u < 4; ++u)
            av[u] = *reinterpret_cast<const float4*>(xrow + k0 + (asb + u) * 4);
        #pragma unroll
        for (int rep = 0; rep < 4; ++rep) {
            const int e  = rep * 256 + tid;
            const int bk = e >> 5, bc = (e & 31) * 4;
            bv[rep] = *reinterpret_cast<const float4*>(w + (size_t)(k0 + bk) * 768 + n0 + bc);
        }
    };

    auto write_tiles = [&](const int it) {
        const int k0 = it * 32;
        #pragma unroll
        for (int u = 0; u < 4; ++u) {
            const int ka = k0 + (asb + u) * 4;          // absolute channel of av[u].x
            const int kk = (asb + u) * 4;               // k row in LDS
            const float4 u1 = *reinterpret_cast<const float4*>(&u_lds[0][ka & 255]);
            const float4 u2 = *reinterpret_cast<const float4*>(&u_lds[1][ka & 255]);
            const float4 u3 = *reinterpret_cast<const float4*>(&u_lds[2][ka & 255]);
            const float4 u4 = *reinterpret_cast<const float4*>(&u_lds[3][ka & 255]);
            At[kk + 0][ar] = fmaf(u1.x, fmaf(alpha, av[u].x, -delta), fmaf(beta, u2.x, fmaf(-gamma, u3.x, u4.x)));
            At[kk + 1][ar] = fmaf(u1.y, fmaf(alpha, av[u].y, -delta), fmaf(beta, u2.y, fmaf(-gamma, u3.y, u4.y)));
            At[kk + 2][ar] = fmaf(u1.z, fmaf(alpha, av[u].z, -delta), fmaf(beta, u2.z, fmaf(-gamma, u3.z, u4.z)));
            At[kk + 3][ar] = fmaf(u1.w, fmaf(alpha, av[u].w, -delta), fmaf(beta, u2.w, fmaf(-gamma, u3.w, u4.w)));
        }
        #pragma unroll
        for (int rep = 0; rep < 4; ++rep) {
            const int e  = rep * 256 + tid;
            const int bk = e >> 5, bc = (e & 31) * 4;
            *reinterpret_cast<float4*>(&Bt[bk][bc]) = bv[rep];
        }
    };

    load_tiles(0);
    for (int it = 0; it < 8; ++it) {
        __syncthreads();             // previous compute done -> safe to overwrite LDS
        write_tiles(it);
        __syncthreads();
        if (it < 7) load_tiles(it + 1);   // global latency hides under compute
        #pragma unroll
        for (int k = 0; k < 32; ++k) {
            const float4 a0 = *reinterpret_cast<const float4*>(&At[k][ty*8]);
            const float4 a1 = *reinterpret_cast<const float4*>(&At[k][ty*8 + 4]);
            const float4 b0 = *reinterpret_cast<const float4*>(&Bt[k][tx*4]);
            const float4 b1 = *reinterpret_cast<const float4*>(&Bt[k][64 + tx*4]);
            const float a[8] = {a0.x, a0.y, a0.z, a0.w, a1.x, a1.y, a1.z, a1.w};
            const float b[8] = {b0.x, b0.y, b0.z, b0.w, b1.x, b1.y, b1.z, b1.w};
            #pragma unroll
            for (int i = 0; i < 8; ++i) {
                #pragma unroll
                for (int j = 0; j < 8; ++j)
                    acc[i][j] = fmaf(a[i], b[j], acc[i][j]);
            }
        }
    }
    #pragma unroll
    for (int i = 0; i < 8; ++i) {
        float* orow = qkv + (size_t)(tok0 + ty*8 + i) * 768 + n0;
        *reinterpret_cast<float4*>(orow + tx*4) =
            make_float4(acc[i][0], acc[i][1], acc[i][2], acc[i][3]);
        *reinterpret_cast<float4*>(orow + 64 + tx*4) =
            make_float4(acc[i][4], acc[i][5], acc[i][6], acc[i][7]);
    }
}

// -------------------- attention per (patch, head) --------------------
// Group 0 (even i, even j) tiles the image exactly (stride 8, size 8) -> plain store,
// no memset needed. Groups 1-3 RMW; within a group footprints are disjoint -> race-free.
__global__ __launch_bounds__(256) void attn_kernel(
    const float* __restrict__ qkv, float* __restrict__ out,
    int gi, int gj, int nJ, int do_store)
{
    __shared__ float q_lds[64][36];
    __shared__ float k_lds[64][36];
    __shared__ float v_lds[64][36];
    __shared__ float p_lds[64][68];
    const int tid = threadIdx.x;
    const int b  = blockIdx.y;
    const int hd = blockIdx.z;
    const int pi = 2 * (blockIdx.x / nJ) + gi;
    const int pj = 2 * (blockIdx.x % nJ) + gj;
    const int t = tid >> 2, seg = tid & 3;
    const int pr = t >> 3, pc = t & 7;
    const size_t pixbase = ((size_t)((b * 64 + 4*pi + pr) * 64) + (4*pj + pc));
    {
        const size_t base = pixbase * 768 + hd * 32 + seg * 8;
        const float4 qa = *reinterpret_cast<const float4*>(qkv + base);
        const float4 qb = *reinterpret_cast<const float4*>(qkv + base + 4);
        const float4 ka = *reinterpret_cast<const float4*>(qkv + base + 256);
        const float4 kb = *reinterpret_cast<const float4*>(qkv + base + 260);
        const float4 va = *reinterpret_cast<const float4*>(qkv + base + 512);
        const float4 vb = *reinterpret_cast<const float4*>(qkv + base + 516);
        *reinterpret_cast<float4*>(&q_lds[t][seg*8    ]) = qa;
        *reinterpret_cast<float4*>(&q_lds[t][seg*8 + 4]) = qb;
        *reinterpret_cast<float4*>(&k_lds[t][seg*8    ]) = ka;
        *reinterpret_cast<float4*>(&k_lds[t][seg*8 + 4]) = kb;
        *reinterpret_cast<float4*>(&v_lds[t][seg*8    ]) = va;
        *reinterpret_cast<float4*>(&v_lds[t][seg*8 + 4]) = vb;
    }
    __syncthreads();
    const float scale = 0.17677669529663687f;  // 32^-0.5
    float4 q4[8];
    #pragma unroll
    for (int u = 0; u < 8; ++u) q4[u] = *reinterpret_cast<const float4*>(&q_lds[t][u*4]);
    float p[16];
    #pragma unroll
    for (int jj = 0; jj < 16; ++jj) {
        const int jc = seg + jj * 4;
        float a0 = 0.f, a1 = 0.f, a2 = 0.f, a3 = 0.f;
        #pragma unroll
        for (int u = 0; u < 8; ++u) {
            const float4 kv = *reinterpret_cast<const float4*>(&k_lds[jc][u*4]);
            a0 = fmaf(q4[u].x, kv.x, a0);
            a1 = fmaf(q4[u].y, kv.y, a1);
            a2 = fmaf(q4[u].z, kv.z, a2);
            a3 = fmaf(q4[u].w, kv.w, a3);
        }
        p[jj] = ((a0 + a1) + (a2 + a3)) * scale;
    }
    float m = p[0];
    #pragma unroll
    for (int jj = 1; jj < 16; ++jj) m = fmaxf(m, p[jj]);
    m = fmaxf(m, __shfl_xor(m, 1));
    m = fmaxf(m, __shfl_xor(m, 2));
    float s = 0.f;
    #pragma unroll
    for (int jj = 0; jj < 16; ++jj) { p[jj] = __expf(p[jj] - m); s += p[jj]; }
    s += __shfl_xor(s, 1);
    s += __shfl_xor(s, 2);
    const float rs = 1.0f / s;
    #pragma unroll
    for (int jj = 0; jj < 16; ++jj) p_lds[t][seg + jj*4] = p[jj] * rs;
    __syncthreads();
    float4 o0 = make_float4(0,0,0,0), o1 = make_float4(0,0,0,0);
    for (int jc = 0; jc < 64; ++jc) {
        const float a = p_lds[t][jc];
        const float4 v0 = *reinterpret_cast<const float4*>(&v_lds[jc][seg*8]);
        const float4 v1 = *reinterpret_cast<const float4*>(&v_lds[jc][seg*8 + 4]);
        o0.x = fmaf(a, v0.x, o0.x); o0.y = fmaf(a, v0.y, o0.y);
        o0.z = fmaf(a, v0.z, o0.z); o0.w = fmaf(a, v0.w, o0.w);
        o1.x = fmaf(a, v1.x, o1.x); o1.y = fmaf(a, v1.y, o1.y);
        o1.z = fmaf(a, v1.z, o1.z); o1.w = fmaf(a, v1.w, o1.w);
    }
    float* op = out + pixbase * 256 + hd * 32 + seg * 8;
    if (do_store) {
        *reinterpret_cast<float4*>(op)     = o0;
        *reinterpret_cast<float4*>(op + 4) = o1;
    } else {
        float4 c0 = *reinterpret_cast<const float4*>(op);
        float4 c1 = *reinterpret_cast<const float4*>(op + 4);
        c0.x += o0.x; c0.y += o0.y; c0.z += o0.z; c0.w += o0.w;
        c1.x += o1.x; c1.y += o1.y; c1.z += o1.z; c1.w += o1.w;
        *reinterpret_cast<float4*>(op)     = c0;
        *reinterpret_cast<float4*>(op + 4) = c1;
    }
}

// -------------------- out = (acc / counts) @ w_out + b_out, in-place --------------------
__global__ __launch_bounds__(256) void proj_kernel(
    float* __restrict__ out, const float* __restrict__ w, const float* __restrict__ bo)
{
    __shared__ float At[16][36];
    __shared__ float Bt[16][256];
    const int tid  = threadIdx.x;
    const int tok0 = blockIdx.x * 32;
    const int ty = tid >> 5, tx = tid & 31;
    const int st = tid >> 2, sseg = tid & 3;
    const int bc = (tid & 63) * 4, bkb = tid >> 6;
    float ascale = 0.f;
    if (tid < 128) {
        const int token = tok0 + st;
        const int hp = (token >> 6) & 63, wp = token & 63;
        const float cnt = ((hp >= 4 && hp < 60) ? 2.f : 1.f) * ((wp >= 4 && wp < 60) ? 2.f : 1.f);
        ascale = 1.0f / cnt;
    }
    float acc[4][8] = {};
    for (int kk = 0; kk < 16; ++kk) {
        const int k0 = kk * 16;
        float4 av = make_float4(0,0,0,0);
        if (tid < 128)
            av = *reinterpret_cast<const float4*>(out + (size_t)(tok0 + st) * 256 + k0 + sseg * 4);
        float4 wv[4];
        #pragma unroll
        for (int u = 0; u < 4; ++u)
            wv[u] = *reinterpret_cast<const float4*>(w + (size_t)(k0 + bkb*4 + u) * 256 + bc);
        __syncthreads();
        if (tid < 128) {
            At[sseg*4+0][st] = av.x * ascale;
            At[sseg*4+1][st] = av.y * ascale;
            At[sseg*4+2][st] = av.z * ascale;
            At[sseg*4+3][st] = av.w * ascale;
        }
        #pragma unroll
        for (int u = 0; u < 4; ++u)
            *reinterpret_cast<float4*>(&Bt[bkb*4+u][bc]) = wv[u];
        __syncthreads();
        #pragma unroll
        for (int k = 0; k < 16; ++k) {
            const float4 a  = *reinterpret_cast<const float4*>(&At[k][ty*4]);
            const float4 b0 = *reinterpret_cast<const float4*>(&Bt[k][tx*4]);
            const float4 b1 = *reinterpret_cast<const float4*>(&Bt[k][128 + tx*4]);
            acc[0][0] += a.x*b0.x; acc[0][1] += a.x*b0.y; acc[0][2] += a.x*b0.z; acc[0][3] += a.x*b0.w;
            acc[0][4] += a.x*b1.x; acc[0][5] += a.x*b1.y; acc[0][6] += a.x*b1.z; acc[0][7] += a.x*b1.w;
            acc[1][0] += a.y*b0.x; acc[1][1] += a.y*b0.y; acc[1][2] += a.y*b0.z; acc[1][3] += a.y*b0.w;
            acc[1][4] += a.y*b1.x; acc[1][5] += a.y*b1.y; acc[1][6] += a.y*b1.z; acc[1][7] += a.y*b1.w;
            acc[2][0] += a.z*b0.x; acc[2][1] += a.z*b0.y; acc[2][2] += a.z*b0.z; acc[2][3] += a.z*b0.w;
            acc[2][4] += a.z*b1.x; acc[2][5] += a.z*b1.y; acc[2][6] += a.z*b1.z; acc[2][7] += a.z*b1.w;
            acc[3][0] += a.w*b0.x; acc[3][1] += a.w*b0.y; acc[3][2] += a.w*b0.z; acc[3][3] += a.w*b0.w;
            acc[3][4] += a.w*b1.x; acc[3][5] += a.w*b1.y; acc[3][6] += a.w*b1.z; acc[3][7] += a.w*b1.w;
        }
    }
    const float4 bo0 = *reinterpret_cast<const float4*>(bo + tx*4);
    const float4 bo1 = *reinterpret_cast<const float4*>(bo + 128 + tx*4);
    #pragma unroll
    for (int r = 0; r < 4; ++r) {
        float* orow = out + (size_t)(tok0 + ty*4 + r) * 256;
        const float4 o0 = make_float4(acc[r][0]+bo0.x, acc[r][1]+bo0.y, acc[r][2]+bo0.z, acc[r][3]+bo0.w);
        const float4 o1 = make_float4(acc[r][4]+bo1.x, acc[r][5]+bo1.y, acc[r][6]+bo1.z, acc[r][7]+bo1.w);
        *reinterpret_cast<float4*>(orow + tx*4)       = o0;
        *reinterpret_cast<float4*>(orow + 128 + tx*4) = o1;
    }
}

extern "C" void kernel_launch(void* const* d_in, const int* in_sizes, int n_in,
                              void* d_out, int out_size, void* d_ws, size_t ws_size,
                              hipStream_t stream)
{
    const float* x     = (const float*)d_in[0];
    const float* ln1_g = (const float*)d_in[1];
    const float* ln1_b = (const float*)d_in[2];
    const float* ln2_g = (const float*)d_in[3];
    const float* ln2_b = (const float*)d_in[4];
    const float* w_qkv = (const float*)d_in[5];
    const float* w_out = (const float*)d_in[6];
    const float* b_out = (const float*)d_in[7];
    float* out = (float*)d_out;
    float* ws  = (float*)d_ws;

    float4* stats = (float4*)ws;                 // 32768 * 4 floats = 512 KB
    float*  qkv   = ws + (size_t)NTOK * 4;       // 32768 * 768 floats = 96 MB

    ln_stats_kernel<<<NTOK / 4, 256, 0, stream>>>(x, ln1_g, ln1_b, stats);
    qkv_kernel<<<dim3(6, NTOK / 128), 256, 0, stream>>>(
        x, stats, ln1_g, ln1_b, ln2_g, ln2_b, w_qkv, qkv);
    for (int g = 0; g < 4; ++g) {
        const int gi = g >> 1, gj = g & 1;
        const int nI = gi ? 7 : 8, nJ = gj ? 7 : 8;
        attn_kernel<<<dim3(nI * nJ, B_, HEADS_), 256, 0, stream>>>(
            qkv, out, gi, gj, nJ, (g == 0) ? 1 : 0);
    }
    proj_kernel<<<NTOK / 32, 256, 0, stream>>>(out, w_out, b_out);
}

// Round 6
// 459.569 us; speedup vs baseline: 1.0935x; 1.0935x over previous
//
#include <hip/hip_runtime.h>
#include <hip/hip_bf16.h>
#include <cstdint>
#include <cstddef>

#define LN_EPS 1e-5f
#define B_    8
#define HW_   64
#define C_    256
#define NTOK  (B_ * HW_ * HW_)   // 32768
#define HEADS_ 8
#define DH_    32

// -------------------- per-token LN stats --------------------
// stats[tok] = {m1, r1, m2, r2}: LN2(LN1(x)) = ((x-m1)*r1*g1 + b1 - m2)*r2*g2 + b2
__global__ __launch_bounds__(256) void ln_stats_kernel(
    const float* __restrict__ x, const float* __restrict__ g1,
    const float* __restrict__ b1, float4* __restrict__ stats)
{
    const int gid  = blockIdx.x * 256 + threadIdx.x;
    const int tok  = gid >> 6;
    const int lane = gid & 63;
    if (tok >= NTOK) return;
    const float4 xv = reinterpret_cast<const float4*>(x + (size_t)tok * C_)[lane];
    float s  = xv.x + xv.y + xv.z + xv.w;
    float sq = xv.x*xv.x + xv.y*xv.y + xv.z*xv.z + xv.w*xv.w;
    for (int off = 32; off; off >>= 1) {
        s  += __shfl_xor(s, off);
        sq += __shfl_xor(sq, off);
    }
    const float m1 = s * (1.0f / 256.0f);
    const float r1 = rsqrtf(fmaxf(sq * (1.0f / 256.0f) - m1 * m1, 0.0f) + LN_EPS);
    const float4 g = reinterpret_cast<const float4*>(g1)[lane];
    const float4 b = reinterpret_cast<const float4*>(b1)[lane];
    const float y0 = (xv.x - m1) * r1 * g.x + b.x;
    const float y1 = (xv.y - m1) * r1 * g.y + b.y;
    const float y2 = (xv.z - m1) * r1 * g.z + b.z;
    const float y3 = (xv.w - m1) * r1 * g.w + b.w;
    float s2  = y0 + y1 + y2 + y3;
    float sq2 = y0*y0 + y1*y1 + y2*y2 + y3*y3;
    for (int off = 32; off; off >>= 1) {
        s2  += __shfl_xor(s2, off);
        sq2 += __shfl_xor(sq2, off);
    }
    const float m2 = s2 * (1.0f / 256.0f);
    const float r2 = rsqrtf(fmaxf(sq2 * (1.0f / 256.0f) - m2 * m2, 0.0f) + LN_EPS);
    if (lane == 0) stats[tok] = make_float4(m1, r1, m2, r2);
}

// -------------------- qkv = LN2(LN1(x)) @ w_qkv (round-1 kernel: known 193us) ----------
// M=32768, K=256, N=768. BM=BN=64, BK=16, 256 threads, 4x4 microtile.
__global__ __launch_bounds__(256) void qkv_kernel(
    const float* __restrict__ x, const float4* __restrict__ stats,
    const float* __restrict__ g1, const float* __restrict__ b1,
    const float* __restrict__ g2, const float* __restrict__ b2,
    const float* __restrict__ w, float* __restrict__ qkv)
{
    __shared__ float At[16][72];   // [k][token], pad 72 -> conflict-light
    __shared__ float Bt[16][64];   // [k][n]
    const int tid  = threadIdx.x;
    const int tok0 = blockIdx.y * 64;
    const int n0   = blockIdx.x * 64;
    const int ty = tid >> 4, tx = tid & 15;     // microtile: rows ty*4.., cols tx*4..
    const int st = tid >> 2, sseg = tid & 3;    // A staging: token st, k-quad sseg
    const int bk = tid >> 4, bx = tid & 15;     // B staging
    const float4 s4 = stats[tok0 + st];
    const float* xrow = x + (size_t)(tok0 + st) * C_;
    float acc[4][4] = {};
    for (int kk = 0; kk < 16; ++kk) {
        const int k0 = kk * 16;
        const int ka = k0 + sseg * 4;
        const float4 xv  = *reinterpret_cast<const float4*>(xrow + ka);
        const float4 g1v = *reinterpret_cast<const float4*>(g1 + ka);
        const float4 b1v = *reinterpret_cast<const float4*>(b1 + ka);
        const float4 g2v = *reinterpret_cast<const float4*>(g2 + ka);
        const float4 b2v = *reinterpret_cast<const float4*>(b2 + ka);
        const float h0 = ((xv.x - s4.x)*s4.y*g1v.x + b1v.x - s4.z)*s4.w*g2v.x + b2v.x;
        const float h1 = ((xv.y - s4.x)*s4.y*g1v.y + b1v.y - s4.z)*s4.w*g2v.y + b2v.y;
        const float h2 = ((xv.z - s4.x)*s4.y*g1v.z + b1v.z - s4.z)*s4.w*g2v.z + b2v.z;
        const float h3 = ((xv.w - s4.x)*s4.y*g1v.w + b1v.w - s4.z)*s4.w*g2v.w + b2v.w;
        const float4 wv = *reinterpret_cast<const float4*>(w + (size_t)(k0 + bk) * 768 + n0 + bx * 4);
        __syncthreads();
        At[sseg*4+0][st] = h0;
        At[sseg*4+1][st] = h1;
        At[sseg*4+2][st] = h2;
        At[sseg*4+3][st] = h3;
        *reinterpret_cast<float4*>(&Bt[bk][bx*4]) = wv;
        __syncthreads();
        #pragma unroll
        for (int k = 0; k < 16; ++k) {
            const float4 a = *reinterpret_cast<const float4*>(&At[k][ty*4]);
            const float4 b = *reinterpret_cast<const float4*>(&Bt[k][tx*4]);
            acc[0][0] += a.x*b.x; acc[0][1] += a.x*b.y; acc[0][2] += a.x*b.z; acc[0][3] += a.x*b.w;
            acc[1][0] += a.y*b.x; acc[1][1] += a.y*b.y; acc[1][2] += a.y*b.z; acc[1][3] += a.y*b.w;
            acc[2][0] += a.z*b.x; acc[2][1] += a.z*b.y; acc[2][2] += a.z*b.z; acc[2][3] += a.z*b.w;
            acc[3][0] += a.w*b.x; acc[3][1] += a.w*b.y; acc[3][2] += a.w*b.z; acc[3][3] += a.w*b.w;
        }
    }
    #pragma unroll
    for (int r = 0; r < 4; ++r) {
        const float4 o = make_float4(acc[r][0], acc[r][1], acc[r][2], acc[r][3]);
        *reinterpret_cast<float4*>(qkv + (size_t)(tok0 + ty*4 + r) * 768 + n0 + tx*4) = o;
    }
}

// -------------------- attention per (patch, head) --------------------
// Group 0 (even i, even j) tiles the image exactly -> plain store, no memset.
// Groups 1-3 RMW; within a group footprints are disjoint -> race-free.
// QK: K transposed in LDS + 4x4 register blocking (thread = 4 rows x 4 cols),
// softmax max/sum via 16-lane shfl_xor tree, single p_lds write, old PV.
__global__ __launch_bounds__(256) void attn_kernel(
    const float* __restrict__ qkv, float* __restrict__ out,
    int gi, int gj, int nJ, int do_store)
{
    __shared__ float q_lds[64][36];
    __shared__ float kT[32][68];     // [d][token col]
    __shared__ float v_lds[64][36];
    __shared__ float p_lds[64][68];
    const int tid = threadIdx.x;
    const int b  = blockIdx.y;
    const int hd = blockIdx.z;
    const int pi = 2 * (blockIdx.x / nJ) + gi;
    const int pj = 2 * (blockIdx.x % nJ) + gj;
    const int t = tid >> 2, seg = tid & 3;   // staging/PV: token t, 8-float segment seg
    const int pr = t >> 3, pc = t & 7;
    const size_t pixbase = ((size_t)((b * 64 + 4*pi + pr) * 64) + (4*pj + pc));
    {
        const size_t base = pixbase * 768 + hd * 32 + seg * 8;
        const float4 qa = *reinterpret_cast<const float4*>(qkv + base);
        const float4 qb = *reinterpret_cast<const float4*>(qkv + base + 4);
        const float4 ka = *reinterpret_cast<const float4*>(qkv + base + 256);
        const float4 kb = *reinterpret_cast<const float4*>(qkv + base + 260);
        const float4 va = *reinterpret_cast<const float4*>(qkv + base + 512);
        const float4 vb = *reinterpret_cast<const float4*>(qkv + base + 516);
        *reinterpret_cast<float4*>(&q_lds[t][seg*8    ]) = qa;
        *reinterpret_cast<float4*>(&q_lds[t][seg*8 + 4]) = qb;
        *reinterpret_cast<float4*>(&v_lds[t][seg*8    ]) = va;
        *reinterpret_cast<float4*>(&v_lds[t][seg*8 + 4]) = vb;
        const int d0 = seg * 8;
        kT[d0+0][t] = ka.x; kT[d0+1][t] = ka.y; kT[d0+2][t] = ka.z; kT[d0+3][t] = ka.w;
        kT[d0+4][t] = kb.x; kT[d0+5][t] = kb.y; kT[d0+6][t] = kb.z; kT[d0+7][t] = kb.w;
    }
    __syncthreads();
    const float scale = 0.17677669529663687f;  // 32^-0.5
    const int tr = tid >> 4, tc = tid & 15;    // QK blocking: rows tr*4+i, cols tc*4+j
    float s[4][4] = {};
    #pragma unroll
    for (int kk = 0; kk < 4; ++kk) {
        float qreg[4][8];
        #pragma unroll
        for (int i = 0; i < 4; ++i) {
            const float4 qv0 = *reinterpret_cast<const float4*>(&q_lds[tr*4 + i][kk*8]);
            const float4 qv1 = *reinterpret_cast<const float4*>(&q_lds[tr*4 + i][kk*8 + 4]);
            qreg[i][0] = qv0.x; qreg[i][1] = qv0.y; qreg[i][2] = qv0.z; qreg[i][3] = qv0.w;
            qreg[i][4] = qv1.x; qreg[i][5] = qv1.y; qreg[i][6] = qv1.z; qreg[i][7] = qv1.w;
        }
        #pragma unroll
        for (int w = 0; w < 8; ++w) {
            const float4 kv = *reinterpret_cast<const float4*>(&kT[kk*8 + w][tc*4]);
            const float ka[4] = {kv.x, kv.y, kv.z, kv.w};
            #pragma unroll
            for (int i = 0; i < 4; ++i) {
                #pragma unroll
                for (int j = 0; j < 4; ++j)
                    s[i][j] = fmaf(qreg[i][w], ka[j], s[i][j]);
            }
        }
    }
    // softmax over each of the 4 rows (16 threads per row hold 4 cols each)
    float mrow[4], sum[4];
    #pragma unroll
    for (int i = 0; i < 4; ++i) {
        s[i][0] *= scale; s[i][1] *= scale; s[i][2] *= scale; s[i][3] *= scale;
        mrow[i] = fmaxf(fmaxf(s[i][0], s[i][1]), fmaxf(s[i][2], s[i][3]));
    }
    #pragma unroll
    for (int off = 1; off < 16; off <<= 1)
        #pragma unroll
        for (int i = 0; i < 4; ++i)
            mrow[i] = fmaxf(mrow[i], __shfl_xor(mrow[i], off));
    #pragma unroll
    for (int i = 0; i < 4; ++i) {
        sum[i] = 0.f;
        #pragma unroll
        for (int j = 0; j < 4; ++j) {
            s[i][j] = __expf(s[i][j] - mrow[i]);
            sum[i] += s[i][j];
        }
    }
    #pragma unroll
    for (int off = 1; off < 16; off <<= 1)
        #pragma unroll
        for (int i = 0; i < 4; ++i)
            sum[i] += __shfl_xor(sum[i], off);
    #pragma unroll
    for (int i = 0; i < 4; ++i) {
        const float rs = 1.0f / sum[i];
        #pragma unroll
        for (int j = 0; j < 4; ++j)
            p_lds[tr*4 + i][tc*4 + j] = s[i][j] * rs;
    }
    __syncthreads();
    // PV: o[t][seg*8 .. seg*8+7]
    float4 o0 = make_float4(0,0,0,0), o1 = make_float4(0,0,0,0);
    for (int jc = 0; jc < 64; ++jc) {
        const float a = p_lds[t][jc];
        const float4 v0 = *reinterpret_cast<const float4*>(&v_lds[jc][seg*8]);
        const float4 v1 = *reinterpret_cast<const float4*>(&v_lds[jc][seg*8 + 4]);
        o0.x = fmaf(a, v0.x, o0.x); o0.y = fmaf(a, v0.y, o0.y);
        o0.z = fmaf(a, v0.z, o0.z); o0.w = fmaf(a, v0.w, o0.w);
        o1.x = fmaf(a, v1.x, o1.x); o1.y = fmaf(a, v1.y, o1.y);
        o1.z = fmaf(a, v1.z, o1.z); o1.w = fmaf(a, v1.w, o1.w);
    }
    float* op = out + pixbase * 256 + hd * 32 + seg * 8;
    if (do_store) {
        *reinterpret_cast<float4*>(op)     = o0;
        *reinterpret_cast<float4*>(op + 4) = o1;
    } else {
        float4 c0 = *reinterpret_cast<const float4*>(op);
        float4 c1 = *reinterpret_cast<const float4*>(op + 4);
        c0.x += o0.x; c0.y += o0.y; c0.z += o0.z; c0.w += o0.w;
        c1.x += o1.x; c1.y += o1.y; c1.z += o1.z; c1.w += o1.w;
        *reinterpret_cast<float4*>(op)     = c0;
        *reinterpret_cast<float4*>(op + 4) = c1;
    }
}

// -------------------- out = (acc / counts) @ w_out + b_out, in-place --------------------
__global__ __launch_bounds__(256) void proj_kernel(
    float* __restrict__ out, const float* __restrict__ w, const float* __restrict__ bo)
{
    __shared__ float At[16][36];
    __shared__ float Bt[16][256];
    const int tid  = threadIdx.x;
    const int tok0 = blockIdx.x * 32;
    const int ty = tid >> 5, tx = tid & 31;
    const int st = tid >> 2, sseg = tid & 3;
    const int bc = (tid & 63) * 4, bkb = tid >> 6;
    float ascale = 0.f;
    if (tid < 128) {
        const int token = tok0 + st;
        const int hp = (token >> 6) & 63, wp = token & 63;
        const float cnt = ((hp >= 4 && hp < 60) ? 2.f : 1.f) * ((wp >= 4 && wp < 60) ? 2.f : 1.f);
        ascale = 1.0f / cnt;
    }
    float acc[4][8] = {};
    for (int kk = 0; kk < 16; ++kk) {
        const int k0 = kk * 16;
        float4 av = make_float4(0,0,0,0);
        if (tid < 128)
            av = *reinterpret_cast<const float4*>(out + (size_t)(tok0 + st) * 256 + k0 + sseg * 4);
        float4 wv[4];
        #pragma unroll
        for (int u = 0; u < 4; ++u)
            wv[u] = *reinterpret_cast<const float4*>(w + (size_t)(k0 + bkb*4 + u) * 256 + bc);
        __syncthreads();
        if (tid < 128) {
            At[sseg*4+0][st] = av.x * ascale;
            At[sseg*4+1][st] = av.y * ascale;
            At[sseg*4+2][st] = av.z * ascale;
            At[sseg*4+3][st] = av.w * ascale;
        }
        #pragma unroll
        for (int u = 0; u < 4; ++u)
            *reinterpret_cast<float4*>(&Bt[bkb*4+u][bc]) = wv[u];
        __syncthreads();
        #pragma unroll
        for (int k = 0; k < 16; ++k) {
            const float4 a  = *reinterpret_cast<const float4*>(&At[k][ty*4]);
            const float4 b0 = *reinterpret_cast<const float4*>(&Bt[k][tx*4]);
            const float4 b1 = *reinterpret_cast<const float4*>(&Bt[k][128 + tx*4]);
            acc[0][0] += a.x*b0.x; acc[0][1] += a.x*b0.y; acc[0][2] += a.x*b0.z; acc[0][3] += a.x*b0.w;
            acc[0][4] += a.x*b1.x; acc[0][5] += a.x*b1.y; acc[0][6] += a.x*b1.z; acc[0][7] += a.x*b1.w;
            acc[1][0] += a.y*b0.x; acc[1][1] += a.y*b0.y; acc[1][2] += a.y*b0.z; acc[1][3] += a.y*b0.w;
            acc[1][4] += a.y*b1.x; acc[1][5] += a.y*b1.y; acc[1][6] += a.y*b1.z; acc[1][7] += a.y*b1.w;
            acc[2][0] += a.z*b0.x; acc[2][1] += a.z*b0.y; acc[2][2] += a.z*b0.z; acc[2][3] += a.z*b0.w;
            acc[2][4] += a.z*b1.x; acc[2][5] += a.z*b1.y; acc[2][6] += a.z*b1.z; acc[2][7] += a.z*b1.w;
            acc[3][0] += a.w*b0.x; acc[3][1] += a.w*b0.y; acc[3][2] += a.w*b0.z; acc[3][3] += a.w*b0.w;
            acc[3][4] += a.w*b1.x; acc[3][5] += a.w*b1.y; acc[3][6] += a.w*b1.z; acc[3][7] += a.w*b1.w;
        }
    }
    const float4 bo0 = *reinterpret_cast<const float4*>(bo + tx*4);
    const float4 bo1 = *reinterpret_cast<const float4*>(bo + 128 + tx*4);
    #pragma unroll
    for (int r = 0; r < 4; ++r) {
        float* orow = out + (size_t)(tok0 + ty*4 + r) * 256;
        const float4 o0 = make_float4(acc[r][0]+bo0.x, acc[r][1]+bo0.y, acc[r][2]+bo0.z, acc[r][3]+bo0.w);
        const float4 o1 = make_float4(acc[r][4]+bo1.x, acc[r][5]+bo1.y, acc[r][6]+bo1.z, acc[r][7]+bo1.w);
        *reinterpret_cast<float4*>(orow + tx*4)       = o0;
        *reinterpret_cast<float4*>(orow + 128 + tx*4) = o1;
    }
}

extern "C" void kernel_launch(void* const* d_in, const int* in_sizes, int n_in,
                              void* d_out, int out_size, void* d_ws, size_t ws_size,
                              hipStream_t stream)
{
    const float* x     = (const float*)d_in[0];
    const float* ln1_g = (const float*)d_in[1];
    const float* ln1_b = (const float*)d_in[2];
    const float* ln2_g = (const float*)d_in[3];
    const float* ln2_b = (const float*)d_in[4];
    const float* w_qkv = (const float*)d_in[5];
    const float* w_out = (const float*)d_in[6];
    const float* b_out = (const float*)d_in[7];
    float* out = (float*)d_out;
    float* ws  = (float*)d_ws;

    float4* stats = (float4*)ws;                 // 32768 * 4 floats = 512 KB
    float*  qkv   = ws + (size_t)NTOK * 4;       // 32768 * 768 floats = 96 MB

    ln_stats_kernel<<<NTOK / 4, 256, 0, stream>>>(x, ln1_g, ln1_b, stats);
    qkv_kernel<<<dim3(12, NTOK / 64), 256, 0, stream>>>(
        x, stats, ln1_g, ln1_b, ln2_g, ln2_b, w_qkv, qkv);
    for (int g = 0; g < 4; ++g) {
        const int gi = g >> 1, gj = g & 1;
        const int nI = gi ? 7 : 8, nJ = gj ? 7 : 8;
        attn_kernel<<<dim3(nI * nJ, B_, HEADS_), 256, 0, stream>>>(
            qkv, out, gi, gj, nJ, (g == 0) ? 1 : 0);
    }
    proj_kernel<<<NTOK / 32, 256, 0, stream>>>(out, w_out, b_out);
}